// Round 9
// baseline (768.949 us; speedup 1.0000x reference)
//
#include <hip/hip_runtime.h>
#include <stdint.h>

typedef _Float16 f16;
typedef _Float16 f16x2 __attribute__((ext_vector_type(2)));
typedef _Float16 f16x8 __attribute__((ext_vector_type(8)));
typedef float f32x4 __attribute__((ext_vector_type(4)));

#define AS1 __attribute__((address_space(1)))
#define AS3 __attribute__((address_space(3)))

#define NN 10000
#define NP 10112
#define KK0 4096
#define FF 512

// ---------------- CSR build (batched over 3 graphs) ----------------
__global__ void k_count_b(const int* __restrict__ d0, const int* __restrict__ d1,
                          const int* __restrict__ d2, int E0, int E1, int E2,
                          int nb0, int nb1, int* __restrict__ deg){
  int b = blockIdx.x;
  const int* d; int Eg, base, lb;
  if (b < nb0){ d=d0; Eg=E0; base=0; lb=b; }
  else if (b < nb0+nb1){ d=d1; Eg=E1; base=NN; lb=b-nb0; }
  else { d=d2; Eg=E2; base=2*NN; lb=b-nb0-nb1; }
  int i = lb*256 + threadIdx.x;
  if (i < Eg) atomicAdd(&deg[base + d[i]], 1);
}

__global__ __launch_bounds__(1024) void k_scan_b(const int* __restrict__ deg_all,
    int* __restrict__ rowptr_all, int* __restrict__ cursor_all){
  int g = blockIdx.x;
  const int* deg = deg_all + g*NN;
  int* rowptr = rowptr_all + g*(NN+1);
  int* cursor = cursor_all + g*NN;
  __shared__ int ps[1024];
  int t = threadIdx.x;
  const int CH = 16;
  int i0 = t*CH;
  int sum = 0;
  for (int k=0;k<CH;k++){ int i=i0+k; if (i<NN) sum += deg[i]; }
  ps[t]=sum; __syncthreads();
  for (int off=1; off<1024; off<<=1){
    int v = (t>=off)? ps[t-off] : 0;
    __syncthreads();
    ps[t] += v;
    __syncthreads();
  }
  int run = ps[t]-sum;
  for (int k=0;k<CH;k++){
    int i=i0+k;
    if (i<=NN) rowptr[i]=run;
    if (i<NN){ cursor[i]=run; run += deg[i]; }
  }
}

__global__ void k_fill_b(const int* __restrict__ s0, const int* __restrict__ d0,
                         const int* __restrict__ s1, const int* __restrict__ d1,
                         const int* __restrict__ s2, const int* __restrict__ d2,
                         int E0, int E1, int E2, int nb0, int nb1,
                         int* __restrict__ cursor_all,
                         int* __restrict__ c0, int* __restrict__ c1, int* __restrict__ c2){
  int b = blockIdx.x;
  const int *s, *d; int Eg, lb; int* cur; int* col;
  if (b < nb0){ s=s0; d=d0; Eg=E0; lb=b; cur=cursor_all; col=c0; }
  else if (b < nb0+nb1){ s=s1; d=d1; Eg=E1; lb=b-nb0; cur=cursor_all+NN; col=c1; }
  else { s=s2; d=d2; Eg=E2; lb=b-nb0-nb1; cur=cursor_all+2*NN; col=c2; }
  int i = lb*256 + threadIdx.x;
  if (i >= Eg) return;
  int slot = atomicAdd(&cur[d[i]], 1);
  col[slot] = s[i];
}

// ---------------- weight prep ----------------
__global__ void k_transpose_t(const float* __restrict__ W, f16* __restrict__ WT,
                              int K, int Nc){
  __shared__ float tile[32][33];
  int n0 = blockIdx.x*32, k0 = blockIdx.y*32;
  int tx = threadIdx.x, ty = threadIdx.y;
  #pragma unroll
  for (int i=0;i<32;i+=8)
    tile[ty+i][tx] = W[(long)(k0+ty+i)*Nc + n0+tx];
  __syncthreads();
  #pragma unroll
  for (int i=0;i<32;i+=8)
    WT[(long)(n0+ty+i)*K + k0+tx] = (f16)tile[tx][ty+i];
}

__global__ void k_pack_wc(const float* __restrict__ Wc, const float* __restrict__ rW,
                          f16* __restrict__ WT){
  int idx = blockIdx.x*256 + threadIdx.x;
  if (idx >= 128*512) return;
  int n = idx >> 9; int k = idx & 511;
  float v = 0.f;
  if (n < 40) v = Wc[k*40 + n];
  else if (n < 80) v = rW[k*40 + (n-40)];
  WT[idx] = (f16)v;
}

// ---------------- wide-tile GEMM: C (Np x 512) = A * B^T, 3 tasks in one grid
// BM=128, BN=512, 512 threads = 8 waves, wave = 128x64 sub-tile = one head.
// A staged in LDS (2 x 16KB dbuf); B loaded DIRECT global->VGPR in fragment
// layout (reg-double-buffered, unroll-2 so all indices static). One barrier
// per iter, lgkm-only drain (CVT); B loads fly across barriers.
template<bool CVT>
__global__ __launch_bounds__(512,1) void k_gemmw(
    const void* __restrict__ A0v, const void* __restrict__ A1v, const void* __restrict__ A2v,
    f16* __restrict__ C0, f16* __restrict__ C1, f16* __restrict__ C2,
    const f16* __restrict__ B,
    const float* __restrict__ alp, const float* __restrict__ arp,
    float* __restrict__ elp, float* __restrict__ erp)
{
  constexpr int K = CVT ? KK0 : FF;
  constexpr int nt = K >> 6;
  __shared__ f16 lds[2][8192];   // A only: 128x64 f16 per buf = 16KB

  const int nwg = gridDim.x;               // 237
  const int qd = nwg>>3, rd = nwg&7;
  const int xcd = blockIdx.x & 7, bx = blockIdx.x >> 3;
  const int wid = (xcd < rd ? xcd*(qd+1) : rd*(qd+1) + (xcd-rd)*qd) + bx;
  const int task = wid / 79;
  const int tr = wid - task*79;

  f16* C = task==0?C0:(task==1?C1:C2);

  const int t = threadIdx.x;
  const int wave = t >> 6, lane = t & 63;
  const int slot = (lane&7) ^ (lane>>3);
  const int arow0 = t >> 3;                 // 0..63 (also covers arow0+64)
  const int ak8 = t & 7;

  // B fragment byte offsets: frag (ks,n): col = wave*64+n*16+(lane&15),
  // k = ks*32 + (lane>>4)*8  (8 contiguous f16 = 16B per lane)
  int boff[2][4];
  #pragma unroll
  for (int ks=0;ks<2;ks++)
    #pragma unroll
    for (int n=0;n<4;n++)
      boff[ks][n] = ((wave*64 + n*16 + (lane&15))*K + ks*32 + ((lane>>4)*8))*2;

  #define BLOAD(kt, SET) { \
    _Pragma("unroll") \
    for (int ks=0;ks<2;ks++) \
      _Pragma("unroll") \
      for (int n=0;n<4;n++) \
        SET[ks][n] = *(const f16x8*)((const char*)B + boff[ks][n] + (kt)*128); \
    }

  // A fragment LDS byte offsets (ks0; ks1 = ^64 — slot bit6 flip)
  int abyte[8];
  #pragma unroll
  for (int m=0;m<8;m++){
    int row = m*16 + (lane&15);
    abyte[m] = row*128 + (((lane>>4)*16) ^ ((row&7)<<4));
  }

  f32x4 zero4 = {0.f,0.f,0.f,0.f};
  f32x4 acc[8][4];
  #pragma unroll
  for (int m=0;m<8;m++)
    #pragma unroll
    for (int n=0;n<4;n++) acc[m][n] = zero4;

  f16x8 bfr0[2][4], bfr1[2][4];

  #define MFMA_T(buf, SET) { \
    const char* Ls = (const char*)&lds[buf][0]; \
    _Pragma("unroll") \
    for (int ks=0;ks<2;ks++){ \
      _Pragma("unroll") \
      for (int m=0;m<8;m++){ \
        f16x8 af = *(const f16x8*)(Ls + (abyte[m] ^ (ks*64))); \
        _Pragma("unroll") \
        for (int n=0;n<4;n++) \
          acc[m][n] = __builtin_amdgcn_mfma_f32_16x16x32_f16(af, SET[ks][n], acc[m][n], 0, 0, 0); \
      } \
    } }

  int cur = 0;
  if constexpr (CVT){
    // ---- fp32 A, reg-staged conversion; B direct-to-reg ----
    const float* Af = task==0?(const float*)A0v:(task==1?(const float*)A1v:(const float*)A2v);
    const float* gA[2];
    bool okA[2];
    #pragma unroll
    for (int s=0;s<2;s++){
      int grow = tr*128 + arow0 + s*64;
      okA[s] = grow < NN;
      gA[s] = Af + (long)(okA[s] ? grow : 0)*KK0 + ak8*8;
    }
    f32x4 arE[2][2];   // [row-slot][half] -- static indices ONLY

    #define LOADA(kt) { \
      _Pragma("unroll") \
      for (int s=0;s<2;s++){ \
        arE[s][0] = *(const f32x4*)(gA[s] + (kt)*64); \
        arE[s][1] = *(const f32x4*)(gA[s] + (kt)*64 + 4); \
      } }
    #define WRITEA(buf) { \
      _Pragma("unroll") \
      for (int s=0;s<2;s++){ \
        int row = arow0 + s*64; \
        f16x8 v; \
        _Pragma("unroll") \
        for (int j=0;j<4;j++){ \
          v[j]   = okA[s] ? (f16)arE[s][0][j] : (f16)0.f; \
          v[4+j] = okA[s] ? (f16)arE[s][1][j] : (f16)0.f; \
        } \
        *(f16x8*)(&lds[buf][row*64 + ((ak8 ^ (arow0&7))*8)]) = v; \
      } }

    LOADA(0);
    BLOAD(0, bfr0);
    WRITEA(0);                 // compiler inserts exact vmcnt for arE
    LOADA(1);
    asm volatile("s_waitcnt lgkmcnt(0)" ::: "memory");
    __builtin_amdgcn_s_barrier();

    #define ITER_CVT(kt, SETCUR, SETNXT) { \
      if ((kt)+1 < nt){ BLOAD((kt)+1, SETNXT); WRITEA(cur^1); } \
      if ((kt)+2 < nt){ LOADA((kt)+2); } \
      MFMA_T(cur, SETCUR); \
      if ((kt)+1 < nt){ \
        asm volatile("s_waitcnt lgkmcnt(0)" ::: "memory"); \
        __builtin_amdgcn_s_barrier(); \
      } \
      cur ^= 1; }

    for (int kt=0; kt<nt; kt+=2){
      ITER_CVT(kt,   bfr0, bfr1);
      ITER_CVT(kt+1, bfr1, bfr0);
    }
    #undef ITER_CVT
    #undef LOADA
    #undef WRITEA
  } else {
    // ---- f16 A via global_load_lds; B direct-to-reg ----
    const f16* Ah = task==0?(const f16*)A0v:(task==1?(const f16*)A1v:(const f16*)A2v);
    const f16* Ab = Ah + (long)tr*128*K;
    const int r8 = lane>>3;

    #define GLDSA(kt, buf) { \
      _Pragma("unroll") \
      for (int s=0;s<2;s++){ \
        int arow = wave*8 + r8 + s*64; \
        __builtin_amdgcn_global_load_lds((const AS1 void*)(Ab + (long)arow*K + (kt)*64 + slot*8), \
            (AS3 void*)(&lds[buf][s*4096 + wave*512]), 16, 0, 0); \
      } }

    GLDSA(0, 0);
    BLOAD(0, bfr0);
    asm volatile("s_waitcnt vmcnt(8) lgkmcnt(0)" ::: "memory");  // drain GLDSA(0); B flying
    __builtin_amdgcn_s_barrier();

    #define ITER_H(kt, SETCUR, SETNXT) { \
      if ((kt)+1 < nt){ GLDSA((kt)+1, cur^1); BLOAD((kt)+1, SETNXT); } \
      MFMA_T(cur, SETCUR); \
      if ((kt)+1 < nt){ \
        asm volatile("s_waitcnt vmcnt(8) lgkmcnt(0)" ::: "memory"); \
        __builtin_amdgcn_s_barrier(); \
      } \
      cur ^= 1; }

    for (int kt=0; kt<nt; kt+=2){
      ITER_H(kt,   bfr0, bfr1);
      ITER_H(kt+1, bfr1, bfr0);
    }
    #undef ITER_H
    #undef GLDSA
  }
  #undef BLOAD
  #undef MFMA_T

  // ---- C write: row = m*16 + (lane>>4)*4 + q, col = wave*64 + n*16 + (lane&15)
  #pragma unroll
  for (int m=0;m<8;m++){
    int row0 = tr*128 + m*16 + ((lane>>4)<<2);
    #pragma unroll
    for (int n=0;n<4;n++){
      int col = wave*64 + n*16 + (lane&15);
      #pragma unroll
      for (int q2=0;q2<4;q2++)
        C[(long)(row0+q2)*FF + col] = (f16)acc[m][n][q2];
    }
  }

  // ---- el/er epilogue: wave == head
  {
    const int head = wave;
    const float* alh = alp + head*64;
    const float* arh = arp + head*64;
    float alv[4], arv[4];
    #pragma unroll
    for (int n=0;n<4;n++){ int d = n*16 + (lane&15); alv[n]=alh[d]; arv[n]=arh[d]; }
    float* elo = elp + (long)task*NN*8;
    float* ero = erp + (long)task*NN*8;
    #pragma unroll
    for (int m=0;m<8;m++){
      float e0,e1,e2,e3,r0,r1,r2,r3;
      #pragma unroll
      for (int qq=0;qq<4;qq++){
        float e=0.f, rr=0.f;
        #pragma unroll
        for (int n=0;n<4;n++){ e += acc[m][n][qq]*alv[n]; rr += acc[m][n][qq]*arv[n]; }
        #pragma unroll
        for (int off=1; off<16; off<<=1){ e += __shfl_xor(e, off); rr += __shfl_xor(rr, off); }
        if (qq==0){e0=e;r0=rr;} else if (qq==1){e1=e;r1=rr;} else if (qq==2){e2=e;r2=rr;} else {e3=e;r3=rr;}
      }
      int qq = lane&15;
      if (qq < 4){
        int node = tr*128 + m*16 + ((lane>>4)<<2) + qq;
        if (node < NN){
          float ev = qq==0?e0:(qq==1?e1:(qq==2?e2:e3));
          float rv = qq==0?r0:(qq==1?r1:(qq==2?r2:r3));
          long o = (long)node*8 + head;
          elo[o] = ev;
          ero[o] = rv;
        }
      }
    }
  }
}

// ---------------- classifier GEMM (4 tasks, Nc=128, K=512) ----------------
struct GemmTasks { const f16* A[4]; const f16* B[4]; f16* C[4]; };

__global__ __launch_bounds__(256,3) void k_gemmb(GemmTasks p, int ntpb, int ntn,
                                                 int Nc, int K){
  __shared__ f16 lds[2][12288];
  const int bid = blockIdx.x;
  const int task = bid / ntpb;
  const int orig = bid - task*ntpb;
  const int q = ntpb >> 3, r = ntpb & 7;
  const int xcd = orig & 7, bx = orig >> 3;
  const int wid = (xcd < r ? xcd*(q+1) : r*(q+1) + (xcd-r)*q) + bx;
  const int tr = wid / ntn, tc = wid - tr*ntn;

  const f16* A = p.A[task];
  const f16* B = p.B[task];
  f16* C = p.C[task];

  const int t = threadIdx.x;
  const int wave = t >> 6, lane = t & 63;
  const int wr = wave >> 1, wc = wave & 1;

  const f16* Ab = A + (long)tr*64*K;
  const f16* Bb = B + (long)tc*128*K;

  const int slot = (lane&7) ^ (lane>>3);
  const int rbase = wave*8 + (lane>>3);

  f32x4 zero4 = {0.f,0.f,0.f,0.f};
  f32x4 acc[2][4];
  #pragma unroll
  for (int m=0;m<2;m++)
    #pragma unroll
    for (int n=0;n<4;n++) acc[m][n] = zero4;

  int abyte[2][2], bbyte[2][4];
  #pragma unroll
  for (int ks=0;ks<2;ks++){
    #pragma unroll
    for (int m=0;m<2;m++){
      int row = wr*32 + m*16 + (lane&15);
      abyte[ks][m] = row*128 + (((ks*4 + (lane>>4))*16) ^ ((row&7)<<4));
    }
    #pragma unroll
    for (int n=0;n<4;n++){
      int brow = wc*64 + n*16 + (lane&15);
      bbyte[ks][n] = 8192 + brow*128 + (((ks*4 + (lane>>4))*16) ^ ((brow&7)<<4));
    }
  }

  const int nt = K >> 6;
  int cur = 0;

  #pragma unroll
  for (int i=0;i<2;i++)
    __builtin_amdgcn_global_load_lds((const AS1 void*)(Ab + (i*32+rbase)*K + slot*8),
        (AS3 void*)(&lds[0][i*2048 + wave*512]), 16, 0, 0);
  #pragma unroll
  for (int i=0;i<4;i++)
    __builtin_amdgcn_global_load_lds((const AS1 void*)(Bb + (i*32+rbase)*K + slot*8),
        (AS3 void*)(&lds[0][4096 + i*2048 + wave*512]), 16, 0, 0);
  __syncthreads();

  for (int kt=0; kt<nt; kt++){
    if (kt+1 < nt){
      int ko = (kt+1)<<6;
      #pragma unroll
      for (int i=0;i<2;i++)
        __builtin_amdgcn_global_load_lds((const AS1 void*)(Ab + ko + (i*32+rbase)*K + slot*8),
            (AS3 void*)(&lds[cur^1][i*2048 + wave*512]), 16, 0, 0);
      #pragma unroll
      for (int i=0;i<4;i++)
        __builtin_amdgcn_global_load_lds((const AS1 void*)(Bb + ko + (i*32+rbase)*K + slot*8),
            (AS3 void*)(&lds[cur^1][4096 + i*2048 + wave*512]), 16, 0, 0);
    }
    const char* Ls = (const char*)&lds[cur][0];
    #pragma unroll
    for (int ks=0;ks<2;ks++){
      f16x8 af[2], bf[4];
      #pragma unroll
      for (int m=0;m<2;m++) af[m] = *(const f16x8*)(Ls + abyte[ks][m]);
      #pragma unroll
      for (int n=0;n<4;n++) bf[n] = *(const f16x8*)(Ls + bbyte[ks][n]);
      #pragma unroll
      for (int m=0;m<2;m++)
        #pragma unroll
        for (int n=0;n<4;n++)
          acc[m][n] = __builtin_amdgcn_mfma_f32_16x16x32_f16(af[m], bf[n], acc[m][n], 0, 0, 0);
    }
    __syncthreads();
    cur ^= 1;
  }

  #pragma unroll
  for (int m=0;m<2;m++){
    int row0 = tr*64 + wr*32 + m*16 + ((lane>>4)<<2);
    #pragma unroll
    for (int n=0;n<4;n++){
      int col = tc*128 + wc*64 + n*16 + (lane&15);
      #pragma unroll
      for (int q2=0;q2<4;q2++)
        C[(long)(row0+q2)*Nc + col] = (f16)acc[m][n][q2];
    }
  }
}

// ---------------- attention aggregation (batched over graphs) ----------------
#define MAXD 128

struct AggArgs {
  const int* rp[3]; const int* cs[3];
  const float* el; const float* er;
  const f16* feat[3];
  const float* bias;
  f16* outH[3];
  float* outF[3];
};

__global__ __launch_bounds__(256) void k_agg_b(AggArgs a){
  int b = blockIdx.x;
  int g = b / NN, n = b - g*NN;
  const int* rowptr = a.rp[g];
  const int* colsrc = a.cs[g];
  const float* el = a.el + (long)g*NN*8;
  const f16* featH = a.feat[g];
  int t = threadIdx.x;
  __shared__ float sm[MAXD*8];
  __shared__ int   scol[MAXD];
  __shared__ float red[256];
  __shared__ float inv[8];
  __shared__ float ern[8];
  if (t < 8) ern[t] = a.er[((long)g*NN+n)*8+t];
  __syncthreads();
  int j0 = rowptr[n], deg = rowptr[n+1]-j0;
  int h2 = t >> 5;
  int c = t*2;
  float a0=0.f, a1=0.f;

  if (deg <= MAXD){
    {
      int h = t & 7;
      float dsum = 0.f;
      for (int jj = t>>3; jj < deg; jj += 32){
        int s = colsrc[j0+jj];
        float v = el[s*8+h] + ern[h];
        v = (v>0.f)? v : 0.2f*v;
        float ex = __expf(v);
        dsum += ex;
        sm[jj*8+h] = ex;
        if (h==0) scol[jj] = s;
      }
      red[t] = dsum; __syncthreads();
      if (t<128) red[t] += red[t+128]; __syncthreads();
      if (t<64)  red[t] += red[t+64];  __syncthreads();
      if (t<32)  red[t] += red[t+32];  __syncthreads();
      if (t<16)  red[t] += red[t+16];  __syncthreads();
      if (t<8)   inv[t] = 1.0f / (red[t] + red[t+8]);
      __syncthreads();
    }
    float ivh = inv[h2];
    int jj = 0;
    for (; jj+4<=deg; jj+=4){
      int s0=scol[jj], s1=scol[jj+1], s2=scol[jj+2], s3=scol[jj+3];
      float x0=sm[(jj+0)*8+h2], x1=sm[(jj+1)*8+h2], x2=sm[(jj+2)*8+h2], x3=sm[(jj+3)*8+h2];
      f16x2 f0 = *(const f16x2*)(featH + (long)s0*FF + c);
      f16x2 f1 = *(const f16x2*)(featH + (long)s1*FF + c);
      f16x2 f2 = *(const f16x2*)(featH + (long)s2*FF + c);
      f16x2 f3 = *(const f16x2*)(featH + (long)s3*FF + c);
      a0 += x0*(float)f0[0] + x1*(float)f1[0] + x2*(float)f2[0] + x3*(float)f3[0];
      a1 += x0*(float)f0[1] + x1*(float)f1[1] + x2*(float)f2[1] + x3*(float)f3[1];
    }
    for (; jj<deg; jj++){
      int s = scol[jj];
      float x = sm[jj*8+h2];
      f16x2 f = *(const f16x2*)(featH + (long)s*FF + c);
      a0 += x*(float)f[0];
      a1 += x*(float)f[1];
    }
    a0 *= ivh; a1 *= ivh;
  } else {
    {
      int h = t & 7;
      float dsum = 0.f;
      for (int jj = t>>3; jj < deg; jj += 32){
        int s = colsrc[j0+jj];
        float v = el[s*8+h] + ern[h];
        v = (v>0.f)? v : 0.2f*v;
        float ex = __expf(v);
        dsum += ex;
        if (jj < MAXD){
          sm[jj*8+h] = ex;
          if (h==0) scol[jj] = s;
        }
      }
      red[t] = dsum; __syncthreads();
      if (t<128) red[t] += red[t+128]; __syncthreads();
      if (t<64)  red[t] += red[t+64];  __syncthreads();
      if (t<32)  red[t] += red[t+32];  __syncthreads();
      if (t<16)  red[t] += red[t+16];  __syncthreads();
      if (t<8)   inv[t] = 1.0f / (red[t] + red[t+8]);
      __syncthreads();
    }
    float ivh = inv[h2];
    for (int jj=0; jj<deg; jj++){
      int s; float ex;
      if (jj < MAXD){ s = scol[jj]; ex = sm[jj*8+h2]; }
      else {
        s = colsrc[j0+jj];
        float v = el[s*8+h2] + ern[h2];
        v = (v>0.f)? v : 0.2f*v;
        ex = __expf(v);
      }
      float alpha = ex * ivh;
      f16x2 f = *(const f16x2*)(featH + (long)s*FF + c);
      a0 += alpha*(float)f[0];
      a1 += alpha*(float)f[1];
    }
  }

  a0 += a.bias[c]; a1 += a.bias[c+1];
  a0 = (a0>0.f)? a0 : __expf(a0)-1.f;
  a1 = (a1>0.f)? a1 : __expf(a1)-1.f;
  f16x2 o; o[0]=(f16)a0; o[1]=(f16)a1;
  *(f16x2*)(a.outH[g] + (long)n*FF + c) = o;
  float* oF = a.outF[g];
  if (oF){
    oF[(long)n*FF + c]     = a0;
    oF[(long)n*FF + c + 1] = a1;
  }
}

// classifier el/er over 4 tasks
__global__ void k_elerc_b(const f16* __restrict__ fc,
    const float* __restrict__ alc0, const float* __restrict__ arc0,
    const float* __restrict__ alc1, const float* __restrict__ arc1,
    float* __restrict__ el, float* __restrict__ er){
  int idx = blockIdx.x*256 + threadIdx.x;
  if (idx >= 4*NN*8) return;
  int ti = idx / (NN*8);
  int rem = idx - ti*NN*8;
  int n = rem>>3, hh = rem&7;
  const f16* featc = fc + (long)ti*NP*128;
  const float* al = (ti&1) ? alc1 : alc0;
  const float* ar_ = (ti&1) ? arc1 : arc0;
  float a=0.f, bsum=0.f;
  #pragma unroll
  for (int cc=0; cc<5; cc++){
    float v = (float)featc[(long)n*128 + hh*5 + cc];
    a += v*al[hh*5+cc];
    bsum += v*ar_[hh*5+cc];
  }
  el[idx]=a; er[idx]=bsum;
}

struct ClsArgs {
  const int* rp[3]; const int* cs[3];
  const float* el; const float* er;
  const f16* fc;
  const float* bc[2];
  float* pred;
};

__global__ __launch_bounds__(64) void k_cls_b(ClsArgs a){
  int b = blockIdx.x;
  int ti = b / NN, n = b - ti*NN;
  int g = ti<2 ? ti : 2;
  int ci = ti&1;
  const int* rowptr = a.rp[g];
  const int* colsrc = a.cs[g];
  const float* el = a.el + (long)ti*NN*8;
  const f16* featc = a.fc + (long)ti*NP*128;
  const float* bc = a.bc[ci];
  float* pred = a.pred + (long)ti*5*NN;
  int l = threadIdx.x;
  __shared__ float sm[MAXD*8];
  __shared__ int   scol[MAXD];
  __shared__ float inv[8];
  __shared__ float ern[8];
  __shared__ float lg[40];
  if (l<8) ern[l] = a.er[((long)ti*NN+n)*8+l];
  __syncthreads();
  int j0 = rowptr[n], deg = rowptr[n+1]-j0;

  if (deg <= MAXD){
    {
      int h = l & 7;
      float dsum = 0.f;
      for (int jj = l>>3; jj < deg; jj += 8){
        int s = colsrc[j0+jj];
        float v = el[s*8+h] + ern[h];
        v = (v>0.f)? v : 0.2f*v;
        float ex = __expf(v);
        dsum += ex;
        sm[jj*8+h] = ex;
        if (h==0) scol[jj] = s;
      }
      dsum += __shfl_xor(dsum, 8);
      dsum += __shfl_xor(dsum, 16);
      dsum += __shfl_xor(dsum, 32);
      if (l<8) inv[l] = 1.0f/dsum;
    }
    __syncthreads();
    if (l<40){
      int h = l/5;
      float ivh = inv[h];
      float acc = 0.f;
      int jj = 0;
      for (; jj+4<=deg; jj+=4){
        int s0=scol[jj], s1=scol[jj+1], s2=scol[jj+2], s3=scol[jj+3];
        float x0=sm[(jj+0)*8+h], x1=sm[(jj+1)*8+h], x2=sm[(jj+2)*8+h], x3=sm[(jj+3)*8+h];
        float v0=(float)featc[(long)s0*128 + l];
        float v1=(float)featc[(long)s1*128 + l];
        float v2=(float)featc[(long)s2*128 + l];
        float v3=(float)featc[(long)s3*128 + l];
        acc += x0*v0 + x1*v1 + x2*v2 + x3*v3;
      }
      for (; jj<deg; jj++)
        acc += sm[jj*8+h] * (float)featc[(long)scol[jj]*128 + l];
      acc *= ivh;
      acc += (float)featc[(long)n*128 + 40 + l];
      acc += bc[l];
      lg[l] = acc;
    }
  } else {
    {
      int h = l & 7;
      float dsum = 0.f;
      for (int jj = l>>3; jj < deg; jj += 8){
        int s = colsrc[j0+jj];
        float v = el[s*8+h] + ern[h];
        v = (v>0.f)? v : 0.2f*v;
        float ex = __expf(v);
        dsum += ex;
        if (jj < MAXD){
          sm[jj*8+h] = ex;
          if (h==0) scol[jj] = s;
        }
      }
      dsum += __shfl_xor(dsum, 8);
      dsum += __shfl_xor(dsum, 16);
      dsum += __shfl_xor(dsum, 32);
      if (l<8) inv[l] = 1.0f/dsum;
    }
    __syncthreads();
    if (l<40){
      int h = l/5;
      float ivh = inv[h];
      float acc = 0.f;
      for (int jj=0; jj<deg; jj++){
        int s; float ex;
        if (jj < MAXD){ s = scol[jj]; ex = sm[jj*8+h]; }
        else {
          s = colsrc[j0+jj];
          float v = el[s*8+h] + ern[h];
          v = (v>0.f)? v : 0.2f*v;
          ex = __expf(v);
        }
        acc += ex*ivh * (float)featc[(long)s*128 + l];
      }
      acc += (float)featc[(long)n*128 + 40 + l];
      acc += bc[l];
      lg[l] = acc;
    }
  }
  __syncthreads();
  if (l<5){
    float p=0.f;
    #pragma unroll
    for (int h=0;h<8;h++) p += lg[h*5+l];
    pred[(long)n*5 + l] = p*0.125f;
  }
}

// ---------------- host orchestration ----------------
extern "C" void kernel_launch(void* const* d_in, const int* in_sizes, int n_in,
                              void* d_out, int out_size, void* d_ws, size_t ws_size,
                              hipStream_t stream){
  const int* srcs[3] = {(const int*)d_in[0], (const int*)d_in[2], (const int*)d_in[4]};
  const int* dsts[3] = {(const int*)d_in[1], (const int*)d_in[3], (const int*)d_in[5]};
  int E[3] = {in_sizes[0], in_sizes[2], in_sizes[4]};
  const float* X[3] = {(const float*)d_in[6], (const float*)d_in[7], (const float*)d_in[8]};
  const float* W0  = (const float*)d_in[9];
  const float* al0 = (const float*)d_in[10];
  const float* ar0 = (const float*)d_in[11];
  const float* b0  = (const float*)d_in[12];
  const float* W1  = (const float*)d_in[13];
  const float* al1 = (const float*)d_in[14];
  const float* ar1 = (const float*)d_in[15];
  const float* b1  = (const float*)d_in[16];
  const float* Wcv[2] = {(const float*)d_in[17], (const float*)d_in[22]};
  const float* alc[2] = {(const float*)d_in[18], (const float*)d_in[23]};
  const float* arc[2] = {(const float*)d_in[19], (const float*)d_in[24]};
  const float* bcv[2] = {(const float*)d_in[20], (const float*)d_in[25]};
  const float* rWv[2] = {(const float*)d_in[21], (const float*)d_in[26]};

  float* out = (float*)d_out;
  float* embOut[3] = {out+200000, out+200000+(long)NN*FF, out+200000+2L*NN*FF};

  char* w = (char*)d_ws;
  size_t off = 0;
  auto alloc = [&](size_t bytes)->void*{
    void* p = (void*)(w + off);
    off += (bytes + 255) & ~((size_t)255);
    return p;
  };
  f16* W0T = (f16*)alloc((size_t)FF*KK0*2);
  f16* W1T = (f16*)alloc((size_t)FF*FF*2);
  f16* WcT[2] = {(f16*)alloc(128*512*2), (f16*)alloc(128*512*2)};
  f16* feat0H[3], *h0H[3], *feat1H[3], *embH[3];
  for (int g=0;g<3;g++) feat0H[g] = (f16*)alloc((size_t)NP*FF*2);
  for (int g=0;g<3;g++) h0H[g]    = (f16*)alloc((size_t)NP*FF*2);
  for (int g=0;g<3;g++) feat1H[g] = (f16*)alloc((size_t)NP*FF*2);
  for (int g=0;g<3;g++) embH[g]   = (f16*)alloc((size_t)NP*FF*2);
  f16* featc = (f16*)alloc((size_t)4*NP*128*2);
  float* el_e = (float*)alloc((size_t)3*NN*8*4);
  float* er_e = (float*)alloc((size_t)3*NN*8*4);
  float* el_c = (float*)alloc((size_t)4*NN*8*4);
  float* er_c = (float*)alloc((size_t)4*NN*8*4);
  int* deg    = (int*)alloc((size_t)3*NN*4);
  int* cursor = (int*)alloc((size_t)3*NN*4);
  int* rowptr = (int*)alloc((size_t)3*(NN+1)*4);
  int* colsrc[3];
  for (int g=0;g<3;g++) colsrc[g] = (int*)alloc((size_t)E[g]*4);
  (void)ws_size; (void)n_in; (void)out_size;

  // ---- CSR (3 graphs, batched) ----
  int nb[3] = {(E[0]+255)/256, (E[1]+255)/256, (E[2]+255)/256};
  hipMemsetAsync(deg, 0, (size_t)3*NN*4, stream);
  k_count_b<<<nb[0]+nb[1]+nb[2], 256, 0, stream>>>(dsts[0], dsts[1], dsts[2],
      E[0], E[1], E[2], nb[0], nb[1], deg);
  k_scan_b<<<3, 1024, 0, stream>>>(deg, rowptr, cursor);
  k_fill_b<<<nb[0]+nb[1]+nb[2], 256, 0, stream>>>(srcs[0], dsts[0], srcs[1], dsts[1],
      srcs[2], dsts[2], E[0], E[1], E[2], nb[0], nb[1], cursor,
      colsrc[0], colsrc[1], colsrc[2]);

  // ---- weight prep ----
  k_transpose_t<<<dim3(FF/32, KK0/32), dim3(32,8), 0, stream>>>(W0, W0T, KK0, FF);
  k_transpose_t<<<dim3(FF/32, FF/32), dim3(32,8), 0, stream>>>(W1, W1T, FF, FF);
  k_pack_wc<<<(128*512+255)/256, 256, 0, stream>>>(Wcv[0], rWv[0], WcT[0]);
  k_pack_wc<<<(128*512+255)/256, 256, 0, stream>>>(Wcv[1], rWv[1], WcT[1]);

  const int* rp[3] = {rowptr, rowptr+(NN+1), rowptr+2*(NN+1)};

  // ---- layer 0: fused convert+GEMM+eler (wide tile), then aggregation ----
  k_gemmw<true><<<237, 512, 0, stream>>>(X[0], X[1], X[2],
      feat0H[0], feat0H[1], feat0H[2], W0T, al0, ar0, el_e, er_e);
  {
    AggArgs a;
    for (int g=0;g<3;g++){ a.rp[g]=rp[g]; a.cs[g]=colsrc[g]; a.feat[g]=feat0H[g];
                           a.outH[g]=h0H[g]; a.outF[g]=nullptr; }
    a.el = el_e; a.er = er_e; a.bias = b0;
    k_agg_b<<<3*NN, 256, 0, stream>>>(a);
  }

  // ---- layer 1: wide-tile GEMM+eler, then aggregation ----
  k_gemmw<false><<<237, 512, 0, stream>>>(h0H[0], h0H[1], h0H[2],
      feat1H[0], feat1H[1], feat1H[2], W1T, al1, ar1, el_e, er_e);
  {
    AggArgs a;
    for (int g=0;g<3;g++){ a.rp[g]=rp[g]; a.cs[g]=colsrc[g]; a.feat[g]=feat1H[g];
                           a.outH[g]=embH[g]; a.outF[g]=embOut[g]; }
    a.el = el_e; a.er = er_e; a.bias = b1;
    k_agg_b<<<3*NN, 256, 0, stream>>>(a);
  }

  // ---- classifiers (4 tasks batched): (g,c) = (0,0),(1,1),(2,0),(2,1) ----
  {
    GemmTasks p;
    const int tg[4] = {0,1,2,2};
    for (int i=0;i<4;i++){ p.A[i]=embH[tg[i]]; p.B[i]=WcT[i&1]; p.C[i]=featc + (long)i*NP*128; }
    k_gemmb<<<4*158, 256, 0, stream>>>(p, 158, 1, 128, FF);
  }
  k_elerc_b<<<(4*NN*8+255)/256, 256, 0, stream>>>(featc, alc[0], arc[0], alc[1], arc[1], el_c, er_c);
  {
    ClsArgs a;
    for (int g=0;g<3;g++){ a.rp[g]=rp[g]; a.cs[g]=colsrc[g]; }
    a.el = el_c; a.er = er_c; a.fc = featc;
    a.bc[0] = bcv[0]; a.bc[1] = bcv[1];
    a.pred = out;
    k_cls_b<<<4*NN, 64, 0, stream>>>(a);
  }
}

// Round 10
// 499.601 us; speedup vs baseline: 1.5391x; 1.5391x over previous
//
#include <hip/hip_runtime.h>
#include <stdint.h>

typedef _Float16 f16;
typedef _Float16 f16x2 __attribute__((ext_vector_type(2)));
typedef _Float16 f16x8 __attribute__((ext_vector_type(8)));
typedef float f32x4 __attribute__((ext_vector_type(4)));

#define AS1 __attribute__((address_space(1)))
#define AS3 __attribute__((address_space(3)))

#define NN 10000
#define NP 10112
#define KK0 4096
#define FF 512

// ---------------- CSR build (batched over 3 graphs) ----------------
__global__ void k_count_b(const int* __restrict__ d0, const int* __restrict__ d1,
                          const int* __restrict__ d2, int E0, int E1, int E2,
                          int nb0, int nb1, int* __restrict__ deg){
  int b = blockIdx.x;
  const int* d; int Eg, base, lb;
  if (b < nb0){ d=d0; Eg=E0; base=0; lb=b; }
  else if (b < nb0+nb1){ d=d1; Eg=E1; base=NN; lb=b-nb0; }
  else { d=d2; Eg=E2; base=2*NN; lb=b-nb0-nb1; }
  int i = lb*256 + threadIdx.x;
  if (i < Eg) atomicAdd(&deg[base + d[i]], 1);
}

__global__ __launch_bounds__(1024) void k_scan_b(const int* __restrict__ deg_all,
    int* __restrict__ rowptr_all, int* __restrict__ cursor_all){
  int g = blockIdx.x;
  const int* deg = deg_all + g*NN;
  int* rowptr = rowptr_all + g*(NN+1);
  int* cursor = cursor_all + g*NN;
  __shared__ int ps[1024];
  int t = threadIdx.x;
  const int CH = 16;
  int i0 = t*CH;
  int sum = 0;
  for (int k=0;k<CH;k++){ int i=i0+k; if (i<NN) sum += deg[i]; }
  ps[t]=sum; __syncthreads();
  for (int off=1; off<1024; off<<=1){
    int v = (t>=off)? ps[t-off] : 0;
    __syncthreads();
    ps[t] += v;
    __syncthreads();
  }
  int run = ps[t]-sum;
  for (int k=0;k<CH;k++){
    int i=i0+k;
    if (i<=NN) rowptr[i]=run;
    if (i<NN){ cursor[i]=run; run += deg[i]; }
  }
}

__global__ void k_fill_b(const int* __restrict__ s0, const int* __restrict__ d0,
                         const int* __restrict__ s1, const int* __restrict__ d1,
                         const int* __restrict__ s2, const int* __restrict__ d2,
                         int E0, int E1, int E2, int nb0, int nb1,
                         int* __restrict__ cursor_all,
                         int* __restrict__ c0, int* __restrict__ c1, int* __restrict__ c2){
  int b = blockIdx.x;
  const int *s, *d; int Eg, lb; int* cur; int* col;
  if (b < nb0){ s=s0; d=d0; Eg=E0; lb=b; cur=cursor_all; col=c0; }
  else if (b < nb0+nb1){ s=s1; d=d1; Eg=E1; lb=b-nb0; cur=cursor_all+NN; col=c1; }
  else { s=s2; d=d2; Eg=E2; lb=b-nb0-nb1; cur=cursor_all+2*NN; col=c2; }
  int i = lb*256 + threadIdx.x;
  if (i >= Eg) return;
  int slot = atomicAdd(&cur[d[i]], 1);
  col[slot] = s[i];
}

// ---------------- weight prep ----------------
__global__ void k_transpose_t(const float* __restrict__ W, f16* __restrict__ WT,
                              int K, int Nc){
  __shared__ float tile[32][33];
  int n0 = blockIdx.x*32, k0 = blockIdx.y*32;
  int tx = threadIdx.x, ty = threadIdx.y;
  #pragma unroll
  for (int i=0;i<32;i+=8)
    tile[ty+i][tx] = W[(long)(k0+ty+i)*Nc + n0+tx];
  __syncthreads();
  #pragma unroll
  for (int i=0;i<32;i+=8)
    WT[(long)(n0+ty+i)*K + k0+tx] = (f16)tile[tx][ty+i];
}

__global__ void k_pack_wc(const float* __restrict__ Wc, const float* __restrict__ rW,
                          f16* __restrict__ WT){
  int idx = blockIdx.x*256 + threadIdx.x;
  if (idx >= 128*512) return;
  int n = idx >> 9; int k = idx & 511;
  float v = 0.f;
  if (n < 40) v = Wc[k*40 + n];
  else if (n < 80) v = rW[k*40 + (n-40)];
  WT[idx] = (f16)v;
}

// ---------------- wide-tile GEMM: C (Np x 512) = A * B^T, 3 tasks in one grid
// BM=128, BN=512, 512 threads = 8 waves, wave = 128x64 sub-tile = one head.
// LDS 2 x (A 16KB + B 64KB) = 160KB. CVT=true: A fp32, reg-staged convert,
// counted-vmcnt pipeline (round-6 proven structure: 186 us).
template<bool CVT>
__global__ __launch_bounds__(512,1) void k_gemmw(
    const void* __restrict__ A0v, const void* __restrict__ A1v, const void* __restrict__ A2v,
    f16* __restrict__ C0, f16* __restrict__ C1, f16* __restrict__ C2,
    const f16* __restrict__ B,
    const float* __restrict__ alp, const float* __restrict__ arp,
    float* __restrict__ elp, float* __restrict__ erp)
{
  constexpr int K = CVT ? KK0 : FF;
  constexpr int nt = K >> 6;
  __shared__ f16 lds[2][40960];   // per buf: A 128x64 (16KB) + B 512x64 (64KB)

  const int nwg = gridDim.x;               // 237
  const int qd = nwg>>3, rd = nwg&7;
  const int xcd = blockIdx.x & 7, bx = blockIdx.x >> 3;
  const int wid = (xcd < rd ? xcd*(qd+1) : rd*(qd+1) + (xcd-rd)*qd) + bx;
  const int task = wid / 79;
  const int tr = wid - task*79;

  f16* C = task==0?C0:(task==1?C1:C2);

  const int t = threadIdx.x;
  const int wave = t >> 6, lane = t & 63;
  const int slot = (lane&7) ^ (lane>>3);
  const int arow0 = t >> 3;                 // 0..63 (also covers arow0+64)
  const int ak8 = t & 7;

  // B staging: 8 x global_load_lds per thread (512 rows x 64 k)
  #define GLDSB(kt, buf) { \
    int ko = (kt)*64; \
    _Pragma("unroll") \
    for (int i=0;i<8;i++){ \
      int br = i*64 + wave*8 + (lane>>3); \
      __builtin_amdgcn_global_load_lds((const AS1 void*)(B + (long)br*K + ko + slot*8), \
          (AS3 void*)(&lds[buf][8192 + i*4096 + wave*512]), 16, 0, 0); \
    } }

  // fragment addresses (byte offsets into lds[buf])
  int abyte[2][8], bbyte[2][4];
  #pragma unroll
  for (int ks=0;ks<2;ks++){
    #pragma unroll
    for (int m=0;m<8;m++){
      int row = m*16 + (lane&15);
      abyte[ks][m] = row*128 + (((ks*4 + (lane>>4))*16) ^ ((row&7)<<4));
    }
    #pragma unroll
    for (int n=0;n<4;n++){
      int brow = wave*64 + n*16 + (lane&15);
      bbyte[ks][n] = 16384 + brow*128 + (((ks*4 + (lane>>4))*16) ^ ((brow&7)<<4));
    }
  }

  f32x4 zero4 = {0.f,0.f,0.f,0.f};
  f32x4 acc[8][4];
  #pragma unroll
  for (int m=0;m<8;m++)
    #pragma unroll
    for (int n=0;n<4;n++) acc[m][n] = zero4;

  #define MFMA_TILE(buf) { \
    const char* Ls = (const char*)&lds[buf][0]; \
    _Pragma("unroll") \
    for (int ks=0;ks<2;ks++){ \
      f16x8 bf[4]; \
      _Pragma("unroll") \
      for (int n=0;n<4;n++) bf[n] = *(const f16x8*)(Ls + bbyte[ks][n]); \
      _Pragma("unroll") \
      for (int m=0;m<8;m++){ \
        f16x8 af = *(const f16x8*)(Ls + abyte[ks][m]); \
        _Pragma("unroll") \
        for (int n=0;n<4;n++) \
          acc[m][n] = __builtin_amdgcn_mfma_f32_16x16x32_f16(af, bf[n], acc[m][n], 0, 0, 0); \
      } \
    } }

  int cur = 0;
  if constexpr (CVT){
    // ---- fp32 A, reg-staged conversion, counted-vmcnt pipeline ----
    const float* Af = task==0?(const float*)A0v:(task==1?(const float*)A1v:(const float*)A2v);
    const float* gA[2];
    bool okA[2];
    #pragma unroll
    for (int s=0;s<2;s++){
      int grow = tr*128 + arow0 + s*64;
      okA[s] = grow < NN;
      gA[s] = Af + (long)(okA[s] ? grow : 0)*KK0 + ak8*8;
    }
    f32x4 arE[2][2];   // [row-slot][half] -- static indices ONLY

    #define LOADA(kt) { \
      _Pragma("unroll") \
      for (int s=0;s<2;s++){ \
        arE[s][0] = *(const f32x4*)(gA[s] + (kt)*64); \
        arE[s][1] = *(const f32x4*)(gA[s] + (kt)*64 + 4); \
      } }
    #define WRITEA(buf) { \
      _Pragma("unroll") \
      for (int s=0;s<2;s++){ \
        int row = arow0 + s*64; \
        f16x8 v; \
        _Pragma("unroll") \
        for (int j=0;j<4;j++){ \
          v[j]   = okA[s] ? (f16)arE[s][0][j] : (f16)0.f; \
          v[4+j] = okA[s] ? (f16)arE[s][1][j] : (f16)0.f; \
        } \
        *(f16x8*)(&lds[buf][row*64 + ((ak8 ^ (arow0&7))*8)]) = v; \
      } }

    LOADA(0);                      // vm: L_A(0)=4
    __builtin_amdgcn_sched_barrier(0);
    GLDSB(0, 0);                   // +8
    __builtin_amdgcn_sched_barrier(0);
    WRITEA(0);                     // compiler waits L_A(0) -> vmcnt(8)
    __builtin_amdgcn_sched_barrier(0);
    LOADA(1);                      // +4
    __builtin_amdgcn_sched_barrier(0);
    asm volatile("s_waitcnt vmcnt(4) lgkmcnt(0)" ::: "memory");  // B staged; L_A(1) flying
    __builtin_amdgcn_s_barrier();

    for (int kt=0; kt<nt; kt++){
      if (kt+1 < nt){
        WRITEA(cur^1);             // waits L_A(kt+1) (only outstanding)
        __builtin_amdgcn_sched_barrier(0);
        GLDSB(kt+1, cur^1);        // +8
        __builtin_amdgcn_sched_barrier(0);
      }
      if (kt+2 < nt){
        LOADA(kt+2);               // +4, after B-stage in queue order
        __builtin_amdgcn_sched_barrier(0);
      }
      MFMA_TILE(cur);
      if (kt+1 < nt){
        __builtin_amdgcn_sched_barrier(0);
        if (kt+2 < nt)
          asm volatile("s_waitcnt vmcnt(4) lgkmcnt(0)" ::: "memory");
        else
          asm volatile("s_waitcnt vmcnt(0) lgkmcnt(0)" ::: "memory");
        __builtin_amdgcn_s_barrier();
      }
      cur ^= 1;
    }
    #undef LOADA
    #undef WRITEA
  } else {
    // ---- f16 A via global_load_lds, simple double-buffered loop ----
    const f16* Ah = task==0?(const f16*)A0v:(task==1?(const f16*)A1v:(const f16*)A2v);
    const f16* Ab = Ah + (long)tr*128*K;
    const int r8 = lane>>3;

    #define GLDSA(kt, buf) { \
      _Pragma("unroll") \
      for (int s=0;s<2;s++){ \
        int arow = wave*8 + r8 + s*64; \
        __builtin_amdgcn_global_load_lds((const AS1 void*)(Ab + (long)arow*K + (kt)*64 + slot*8), \
            (AS3 void*)(&lds[buf][s*4096 + wave*512]), 16, 0, 0); \
      } }

    GLDSA(0, 0);
    GLDSB(0, 0);
    __syncthreads();
    for (int kt=0; kt<nt; kt++){
      if (kt+1 < nt){
        GLDSA(kt+1, cur^1);
        GLDSB(kt+1, cur^1);
      }
      MFMA_TILE(cur);
      __syncthreads();
      cur ^= 1;
    }
    #undef GLDSA
  }
  #undef GLDSB
  #undef MFMA_TILE

  // ---- C write: row = m*16 + (lane>>4)*4 + q, col = wave*64 + n*16 + (lane&15)
  #pragma unroll
  for (int m=0;m<8;m++){
    int row0 = tr*128 + m*16 + ((lane>>4)<<2);
    #pragma unroll
    for (int n=0;n<4;n++){
      int col = wave*64 + n*16 + (lane&15);
      #pragma unroll
      for (int q2=0;q2<4;q2++)
        C[(long)(row0+q2)*FF + col] = (f16)acc[m][n][q2];
    }
  }

  // ---- el/er epilogue: wave == head
  {
    const int head = wave;
    const float* alh = alp + head*64;
    const float* arh = arp + head*64;
    float alv[4], arv[4];
    #pragma unroll
    for (int n=0;n<4;n++){ int d = n*16 + (lane&15); alv[n]=alh[d]; arv[n]=arh[d]; }
    float* elo = elp + (long)task*NN*8;
    float* ero = erp + (long)task*NN*8;
    #pragma unroll
    for (int m=0;m<8;m++){
      float e0,e1,e2,e3,r0,r1,r2,r3;
      #pragma unroll
      for (int qq=0;qq<4;qq++){
        float e=0.f, rr=0.f;
        #pragma unroll
        for (int n=0;n<4;n++){ e += acc[m][n][qq]*alv[n]; rr += acc[m][n][qq]*arv[n]; }
        #pragma unroll
        for (int off=1; off<16; off<<=1){ e += __shfl_xor(e, off); rr += __shfl_xor(rr, off); }
        if (qq==0){e0=e;r0=rr;} else if (qq==1){e1=e;r1=rr;} else if (qq==2){e2=e;r2=rr;} else {e3=e;r3=rr;}
      }
      int qq = lane&15;
      if (qq < 4){
        int node = tr*128 + m*16 + ((lane>>4)<<2) + qq;
        if (node < NN){
          float ev = qq==0?e0:(qq==1?e1:(qq==2?e2:e3));
          float rv = qq==0?r0:(qq==1?r1:(qq==2?r2:r3));
          long o = (long)node*8 + head;
          elo[o] = ev;
          ero[o] = rv;
        }
      }
    }
  }
}

// ---------------- classifier GEMM (4 tasks, Nc=128, K=512) ----------------
struct GemmTasks { const f16* A[4]; const f16* B[4]; f16* C[4]; };

__global__ __launch_bounds__(256,3) void k_gemmb(GemmTasks p, int ntpb, int ntn,
                                                 int Nc, int K){
  __shared__ f16 lds[2][12288];
  const int bid = blockIdx.x;
  const int task = bid / ntpb;
  const int orig = bid - task*ntpb;
  const int q = ntpb >> 3, r = ntpb & 7;
  const int xcd = orig & 7, bx = orig >> 3;
  const int wid = (xcd < r ? xcd*(q+1) : r*(q+1) + (xcd-r)*q) + bx;
  const int tr = wid / ntn, tc = wid - tr*ntn;

  const f16* A = p.A[task];
  const f16* B = p.B[task];
  f16* C = p.C[task];

  const int t = threadIdx.x;
  const int wave = t >> 6, lane = t & 63;
  const int wr = wave >> 1, wc = wave & 1;

  const f16* Ab = A + (long)tr*64*K;
  const f16* Bb = B + (long)tc*128*K;

  const int slot = (lane&7) ^ (lane>>3);
  const int rbase = wave*8 + (lane>>3);

  f32x4 zero4 = {0.f,0.f,0.f,0.f};
  f32x4 acc[2][4];
  #pragma unroll
  for (int m=0;m<2;m++)
    #pragma unroll
    for (int n=0;n<4;n++) acc[m][n] = zero4;

  int abyte[2][2], bbyte[2][4];
  #pragma unroll
  for (int ks=0;ks<2;ks++){
    #pragma unroll
    for (int m=0;m<2;m++){
      int row = wr*32 + m*16 + (lane&15);
      abyte[ks][m] = row*128 + (((ks*4 + (lane>>4))*16) ^ ((row&7)<<4));
    }
    #pragma unroll
    for (int n=0;n<4;n++){
      int brow = wc*64 + n*16 + (lane&15);
      bbyte[ks][n] = 8192 + brow*128 + (((ks*4 + (lane>>4))*16) ^ ((brow&7)<<4));
    }
  }

  const int nt = K >> 6;
  int cur = 0;

  #pragma unroll
  for (int i=0;i<2;i++)
    __builtin_amdgcn_global_load_lds((const AS1 void*)(Ab + (i*32+rbase)*K + slot*8),
        (AS3 void*)(&lds[0][i*2048 + wave*512]), 16, 0, 0);
  #pragma unroll
  for (int i=0;i<4;i++)
    __builtin_amdgcn_global_load_lds((const AS1 void*)(Bb + (i*32+rbase)*K + slot*8),
        (AS3 void*)(&lds[0][4096 + i*2048 + wave*512]), 16, 0, 0);
  __syncthreads();

  for (int kt=0; kt<nt; kt++){
    if (kt+1 < nt){
      int ko = (kt+1)<<6;
      #pragma unroll
      for (int i=0;i<2;i++)
        __builtin_amdgcn_global_load_lds((const AS1 void*)(Ab + ko + (i*32+rbase)*K + slot*8),
            (AS3 void*)(&lds[cur^1][i*2048 + wave*512]), 16, 0, 0);
      #pragma unroll
      for (int i=0;i<4;i++)
        __builtin_amdgcn_global_load_lds((const AS1 void*)(Bb + ko + (i*32+rbase)*K + slot*8),
            (AS3 void*)(&lds[cur^1][4096 + i*2048 + wave*512]), 16, 0, 0);
    }
    const char* Ls = (const char*)&lds[cur][0];
    #pragma unroll
    for (int ks=0;ks<2;ks++){
      f16x8 af[2], bf[4];
      #pragma unroll
      for (int m=0;m<2;m++) af[m] = *(const f16x8*)(Ls + abyte[ks][m]);
      #pragma unroll
      for (int n=0;n<4;n++) bf[n] = *(const f16x8*)(Ls + bbyte[ks][n]);
      #pragma unroll
      for (int m=0;m<2;m++)
        #pragma unroll
        for (int n=0;n<4;n++)
          acc[m][n] = __builtin_amdgcn_mfma_f32_16x16x32_f16(af[m], bf[n], acc[m][n], 0, 0, 0);
    }
    __syncthreads();
    cur ^= 1;
  }

  #pragma unroll
  for (int m=0;m<2;m++){
    int row0 = tr*64 + wr*32 + m*16 + ((lane>>4)<<2);
    #pragma unroll
    for (int n=0;n<4;n++){
      int col = tc*128 + wc*64 + n*16 + (lane&15);
      #pragma unroll
      for (int q2=0;q2<4;q2++)
        C[(long)(row0+q2)*Nc + col] = (f16)acc[m][n][q2];
    }
  }
}

// ---------------- attention aggregation (batched over graphs) ----------------
#define MAXD 128

struct AggArgs {
  const int* rp[3]; const int* cs[3];
  const float* el; const float* er;
  const f16* feat[3];
  const float* bias;
  f16* outH[3];
  float* outF[3];
};

__global__ __launch_bounds__(256) void k_agg_b(AggArgs a){
  int b = blockIdx.x;
  int g = b / NN, n = b - g*NN;
  const int* rowptr = a.rp[g];
  const int* colsrc = a.cs[g];
  const float* el = a.el + (long)g*NN*8;
  const f16* featH = a.feat[g];
  int t = threadIdx.x;
  __shared__ float sm[MAXD*8];
  __shared__ int   scol[MAXD];
  __shared__ float red[256];
  __shared__ float inv[8];
  __shared__ float ern[8];
  if (t < 8) ern[t] = a.er[((long)g*NN+n)*8+t];
  __syncthreads();
  int j0 = rowptr[n], deg = rowptr[n+1]-j0;
  int h2 = t >> 5;
  int c = t*2;
  float a0=0.f, a1=0.f;

  if (deg <= MAXD){
    {
      int h = t & 7;
      float dsum = 0.f;
      for (int jj = t>>3; jj < deg; jj += 32){
        int s = colsrc[j0+jj];
        float v = el[s*8+h] + ern[h];
        v = (v>0.f)? v : 0.2f*v;
        float ex = __expf(v);
        dsum += ex;
        sm[jj*8+h] = ex;
        if (h==0) scol[jj] = s;
      }
      red[t] = dsum; __syncthreads();
      if (t<128) red[t] += red[t+128]; __syncthreads();
      if (t<64)  red[t] += red[t+64];  __syncthreads();
      if (t<32)  red[t] += red[t+32];  __syncthreads();
      if (t<16)  red[t] += red[t+16];  __syncthreads();
      if (t<8)   inv[t] = 1.0f / (red[t] + red[t+8]);
      __syncthreads();
    }
    float ivh = inv[h2];
    int jj = 0;
    for (; jj+4<=deg; jj+=4){
      int s0=scol[jj], s1=scol[jj+1], s2=scol[jj+2], s3=scol[jj+3];
      float x0=sm[(jj+0)*8+h2], x1=sm[(jj+1)*8+h2], x2=sm[(jj+2)*8+h2], x3=sm[(jj+3)*8+h2];
      f16x2 f0 = *(const f16x2*)(featH + (long)s0*FF + c);
      f16x2 f1 = *(const f16x2*)(featH + (long)s1*FF + c);
      f16x2 f2 = *(const f16x2*)(featH + (long)s2*FF + c);
      f16x2 f3 = *(const f16x2*)(featH + (long)s3*FF + c);
      a0 += x0*(float)f0[0] + x1*(float)f1[0] + x2*(float)f2[0] + x3*(float)f3[0];
      a1 += x0*(float)f0[1] + x1*(float)f1[1] + x2*(float)f2[1] + x3*(float)f3[1];
    }
    for (; jj<deg; jj++){
      int s = scol[jj];
      float x = sm[jj*8+h2];
      f16x2 f = *(const f16x2*)(featH + (long)s*FF + c);
      a0 += x*(float)f[0];
      a1 += x*(float)f[1];
    }
    a0 *= ivh; a1 *= ivh;
  } else {
    {
      int h = t & 7;
      float dsum = 0.f;
      for (int jj = t>>3; jj < deg; jj += 32){
        int s = colsrc[j0+jj];
        float v = el[s*8+h] + ern[h];
        v = (v>0.f)? v : 0.2f*v;
        float ex = __expf(v);
        dsum += ex;
        if (jj < MAXD){
          sm[jj*8+h] = ex;
          if (h==0) scol[jj] = s;
        }
      }
      red[t] = dsum; __syncthreads();
      if (t<128) red[t] += red[t+128]; __syncthreads();
      if (t<64)  red[t] += red[t+64];  __syncthreads();
      if (t<32)  red[t] += red[t+32];  __syncthreads();
      if (t<16)  red[t] += red[t+16];  __syncthreads();
      if (t<8)   inv[t] = 1.0f / (red[t] + red[t+8]);
      __syncthreads();
    }
    float ivh = inv[h2];
    for (int jj=0; jj<deg; jj++){
      int s; float ex;
      if (jj < MAXD){ s = scol[jj]; ex = sm[jj*8+h2]; }
      else {
        s = colsrc[j0+jj];
        float v = el[s*8+h2] + ern[h2];
        v = (v>0.f)? v : 0.2f*v;
        ex = __expf(v);
      }
      float alpha = ex * ivh;
      f16x2 f = *(const f16x2*)(featH + (long)s*FF + c);
      a0 += alpha*(float)f[0];
      a1 += alpha*(float)f[1];
    }
  }

  a0 += a.bias[c]; a1 += a.bias[c+1];
  a0 = (a0>0.f)? a0 : __expf(a0)-1.f;
  a1 = (a1>0.f)? a1 : __expf(a1)-1.f;
  f16x2 o; o[0]=(f16)a0; o[1]=(f16)a1;
  *(f16x2*)(a.outH[g] + (long)n*FF + c) = o;
  float* oF = a.outF[g];
  if (oF){
    oF[(long)n*FF + c]     = a0;
    oF[(long)n*FF + c + 1] = a1;
  }
}

// classifier el/er over 4 tasks
__global__ void k_elerc_b(const f16* __restrict__ fc,
    const float* __restrict__ alc0, const float* __restrict__ arc0,
    const float* __restrict__ alc1, const float* __restrict__ arc1,
    float* __restrict__ el, float* __restrict__ er){
  int idx = blockIdx.x*256 + threadIdx.x;
  if (idx >= 4*NN*8) return;
  int ti = idx / (NN*8);
  int rem = idx - ti*NN*8;
  int n = rem>>3, hh = rem&7;
  const f16* featc = fc + (long)ti*NP*128;
  const float* al = (ti&1) ? alc1 : alc0;
  const float* ar_ = (ti&1) ? arc1 : arc0;
  float a=0.f, bsum=0.f;
  #pragma unroll
  for (int cc=0; cc<5; cc++){
    float v = (float)featc[(long)n*128 + hh*5 + cc];
    a += v*al[hh*5+cc];
    bsum += v*ar_[hh*5+cc];
  }
  el[idx]=a; er[idx]=bsum;
}

struct ClsArgs {
  const int* rp[3]; const int* cs[3];
  const float* el; const float* er;
  const f16* fc;
  const float* bc[2];
  float* pred;
};

__global__ __launch_bounds__(64) void k_cls_b(ClsArgs a){
  int b = blockIdx.x;
  int ti = b / NN, n = b - ti*NN;
  int g = ti<2 ? ti : 2;
  int ci = ti&1;
  const int* rowptr = a.rp[g];
  const int* colsrc = a.cs[g];
  const float* el = a.el + (long)ti*NN*8;
  const f16* featc = a.fc + (long)ti*NP*128;
  const float* bc = a.bc[ci];
  float* pred = a.pred + (long)ti*5*NN;
  int l = threadIdx.x;
  __shared__ float sm[MAXD*8];
  __shared__ int   scol[MAXD];
  __shared__ float inv[8];
  __shared__ float ern[8];
  __shared__ float lg[40];
  if (l<8) ern[l] = a.er[((long)ti*NN+n)*8+l];
  __syncthreads();
  int j0 = rowptr[n], deg = rowptr[n+1]-j0;

  if (deg <= MAXD){
    {
      int h = l & 7;
      float dsum = 0.f;
      for (int jj = l>>3; jj < deg; jj += 8){
        int s = colsrc[j0+jj];
        float v = el[s*8+h] + ern[h];
        v = (v>0.f)? v : 0.2f*v;
        float ex = __expf(v);
        dsum += ex;
        sm[jj*8+h] = ex;
        if (h==0) scol[jj] = s;
      }
      dsum += __shfl_xor(dsum, 8);
      dsum += __shfl_xor(dsum, 16);
      dsum += __shfl_xor(dsum, 32);
      if (l<8) inv[l] = 1.0f/dsum;
    }
    __syncthreads();
    if (l<40){
      int h = l/5;
      float ivh = inv[h];
      float acc = 0.f;
      int jj = 0;
      for (; jj+4<=deg; jj+=4){
        int s0=scol[jj], s1=scol[jj+1], s2=scol[jj+2], s3=scol[jj+3];
        float x0=sm[(jj+0)*8+h], x1=sm[(jj+1)*8+h], x2=sm[(jj+2)*8+h], x3=sm[(jj+3)*8+h];
        float v0=(float)featc[(long)s0*128 + l];
        float v1=(float)featc[(long)s1*128 + l];
        float v2=(float)featc[(long)s2*128 + l];
        float v3=(float)featc[(long)s3*128 + l];
        acc += x0*v0 + x1*v1 + x2*v2 + x3*v3;
      }
      for (; jj<deg; jj++)
        acc += sm[jj*8+h] * (float)featc[(long)scol[jj]*128 + l];
      acc *= ivh;
      acc += (float)featc[(long)n*128 + 40 + l];
      acc += bc[l];
      lg[l] = acc;
    }
  } else {
    {
      int h = l & 7;
      float dsum = 0.f;
      for (int jj = l>>3; jj < deg; jj += 8){
        int s = colsrc[j0+jj];
        float v = el[s*8+h] + ern[h];
        v = (v>0.f)? v : 0.2f*v;
        float ex = __expf(v);
        dsum += ex;
        if (jj < MAXD){
          sm[jj*8+h] = ex;
          if (h==0) scol[jj] = s;
        }
      }
      dsum += __shfl_xor(dsum, 8);
      dsum += __shfl_xor(dsum, 16);
      dsum += __shfl_xor(dsum, 32);
      if (l<8) inv[l] = 1.0f/dsum;
    }
    __syncthreads();
    if (l<40){
      int h = l/5;
      float ivh = inv[h];
      float acc = 0.f;
      for (int jj=0; jj<deg; jj++){
        int s; float ex;
        if (jj < MAXD){ s = scol[jj]; ex = sm[jj*8+h]; }
        else {
          s = colsrc[j0+jj];
          float v = el[s*8+h] + ern[h];
          v = (v>0.f)? v : 0.2f*v;
          ex = __expf(v);
        }
        acc += ex*ivh * (float)featc[(long)s*128 + l];
      }
      acc += (float)featc[(long)n*128 + 40 + l];
      acc += bc[l];
      lg[l] = acc;
    }
  }
  __syncthreads();
  if (l<5){
    float p=0.f;
    #pragma unroll
    for (int h=0;h<8;h++) p += lg[h*5+l];
    pred[(long)n*5 + l] = p*0.125f;
  }
}

// ---------------- host orchestration ----------------
extern "C" void kernel_launch(void* const* d_in, const int* in_sizes, int n_in,
                              void* d_out, int out_size, void* d_ws, size_t ws_size,
                              hipStream_t stream){
  const int* srcs[3] = {(const int*)d_in[0], (const int*)d_in[2], (const int*)d_in[4]};
  const int* dsts[3] = {(const int*)d_in[1], (const int*)d_in[3], (const int*)d_in[5]};
  int E[3] = {in_sizes[0], in_sizes[2], in_sizes[4]};
  const float* X[3] = {(const float*)d_in[6], (const float*)d_in[7], (const float*)d_in[8]};
  const float* W0  = (const float*)d_in[9];
  const float* al0 = (const float*)d_in[10];
  const float* ar0 = (const float*)d_in[11];
  const float* b0  = (const float*)d_in[12];
  const float* W1  = (const float*)d_in[13];
  const float* al1 = (const float*)d_in[14];
  const float* ar1 = (const float*)d_in[15];
  const float* b1  = (const float*)d_in[16];
  const float* Wcv[2] = {(const float*)d_in[17], (const float*)d_in[22]};
  const float* alc[2] = {(const float*)d_in[18], (const float*)d_in[23]};
  const float* arc[2] = {(const float*)d_in[19], (const float*)d_in[24]};
  const float* bcv[2] = {(const float*)d_in[20], (const float*)d_in[25]};
  const float* rWv[2] = {(const float*)d_in[21], (const float*)d_in[26]};

  float* out = (float*)d_out;
  float* embOut[3] = {out+200000, out+200000+(long)NN*FF, out+200000+2L*NN*FF};

  char* w = (char*)d_ws;
  size_t off = 0;
  auto alloc = [&](size_t bytes)->void*{
    void* p = (void*)(w + off);
    off += (bytes + 255) & ~((size_t)255);
    return p;
  };
  f16* W0T = (f16*)alloc((size_t)FF*KK0*2);
  f16* W1T = (f16*)alloc((size_t)FF*FF*2);
  f16* WcT[2] = {(f16*)alloc(128*512*2), (f16*)alloc(128*512*2)};
  f16* feat0H[3], *h0H[3], *feat1H[3], *embH[3];
  for (int g=0;g<3;g++) feat0H[g] = (f16*)alloc((size_t)NP*FF*2);
  for (int g=0;g<3;g++) h0H[g]    = (f16*)alloc((size_t)NP*FF*2);
  for (int g=0;g<3;g++) feat1H[g] = (f16*)alloc((size_t)NP*FF*2);
  for (int g=0;g<3;g++) embH[g]   = (f16*)alloc((size_t)NP*FF*2);
  f16* featc = (f16*)alloc((size_t)4*NP*128*2);
  float* el_e = (float*)alloc((size_t)3*NN*8*4);
  float* er_e = (float*)alloc((size_t)3*NN*8*4);
  float* el_c = (float*)alloc((size_t)4*NN*8*4);
  float* er_c = (float*)alloc((size_t)4*NN*8*4);
  int* deg    = (int*)alloc((size_t)3*NN*4);
  int* cursor = (int*)alloc((size_t)3*NN*4);
  int* rowptr = (int*)alloc((size_t)3*(NN+1)*4);
  int* colsrc[3];
  for (int g=0;g<3;g++) colsrc[g] = (int*)alloc((size_t)E[g]*4);
  (void)ws_size; (void)n_in; (void)out_size;

  // ---- CSR (3 graphs, batched) ----
  int nb[3] = {(E[0]+255)/256, (E[1]+255)/256, (E[2]+255)/256};
  hipMemsetAsync(deg, 0, (size_t)3*NN*4, stream);
  k_count_b<<<nb[0]+nb[1]+nb[2], 256, 0, stream>>>(dsts[0], dsts[1], dsts[2],
      E[0], E[1], E[2], nb[0], nb[1], deg);
  k_scan_b<<<3, 1024, 0, stream>>>(deg, rowptr, cursor);
  k_fill_b<<<nb[0]+nb[1]+nb[2], 256, 0, stream>>>(srcs[0], dsts[0], srcs[1], dsts[1],
      srcs[2], dsts[2], E[0], E[1], E[2], nb[0], nb[1], cursor,
      colsrc[0], colsrc[1], colsrc[2]);

  // ---- weight prep ----
  k_transpose_t<<<dim3(FF/32, KK0/32), dim3(32,8), 0, stream>>>(W0, W0T, KK0, FF);
  k_transpose_t<<<dim3(FF/32, FF/32), dim3(32,8), 0, stream>>>(W1, W1T, FF, FF);
  k_pack_wc<<<(128*512+255)/256, 256, 0, stream>>>(Wcv[0], rWv[0], WcT[0]);
  k_pack_wc<<<(128*512+255)/256, 256, 0, stream>>>(Wcv[1], rWv[1], WcT[1]);

  const int* rp[3] = {rowptr, rowptr+(NN+1), rowptr+2*(NN+1)};

  // ---- layer 0: fused convert+GEMM+eler (wide tile), then aggregation ----
  k_gemmw<true><<<237, 512, 0, stream>>>(X[0], X[1], X[2],
      feat0H[0], feat0H[1], feat0H[2], W0T, al0, ar0, el_e, er_e);
  {
    AggArgs a;
    for (int g=0;g<3;g++){ a.rp[g]=rp[g]; a.cs[g]=colsrc[g]; a.feat[g]=feat0H[g];
                           a.outH[g]=h0H[g]; a.outF[g]=nullptr; }
    a.el = el_e; a.er = er_e; a.bias = b0;
    k_agg_b<<<3*NN, 256, 0, stream>>>(a);
  }

  // ---- layer 1: wide-tile GEMM+eler, then aggregation ----
  k_gemmw<false><<<237, 512, 0, stream>>>(h0H[0], h0H[1], h0H[2],
      feat1H[0], feat1H[1], feat1H[2], W1T, al1, ar1, el_e, er_e);
  {
    AggArgs a;
    for (int g=0;g<3;g++){ a.rp[g]=rp[g]; a.cs[g]=colsrc[g]; a.feat[g]=feat1H[g];
                           a.outH[g]=embH[g]; a.outF[g]=embOut[g]; }
    a.el = el_e; a.er = er_e; a.bias = b1;
    k_agg_b<<<3*NN, 256, 0, stream>>>(a);
  }

  // ---- classifiers (4 tasks batched): (g,c) = (0,0),(1,1),(2,0),(2,1) ----
  {
    GemmTasks p;
    const int tg[4] = {0,1,2,2};
    for (int i=0;i<4;i++){ p.A[i]=embH[tg[i]]; p.B[i]=WcT[i&1]; p.C[i]=featc + (long)i*NP*128; }
    k_gemmb<<<4*158, 256, 0, stream>>>(p, 158, 1, 128, FF);
  }
  k_elerc_b<<<(4*NN*8+255)/256, 256, 0, stream>>>(featc, alc[0], arc[0], alc[1], arc[1], el_c, er_c);
  {
    ClsArgs a;
    for (int g=0;g<3;g++){ a.rp[g]=rp[g]; a.cs[g]=colsrc[g]; }
    a.el = el_c; a.er = er_c; a.fc = featc;
    a.bc[0] = bcv[0]; a.bc[1] = bcv[1];
    a.pred = out;
    k_cls_b<<<4*NN, 64, 0, stream>>>(a);
  }
}